// Round 7
// baseline (400.239 us; speedup 1.0000x reference)
//
#include <hip/hip_runtime.h>
#include <math.h>

typedef unsigned short u16;
typedef __bf16 bf16x8 __attribute__((ext_vector_type(8)));
typedef float f32x4 __attribute__((ext_vector_type(4)));
typedef u16 u16x8 __attribute__((ext_vector_type(8)));
typedef u16 u16x4 __attribute__((ext_vector_type(4)));
typedef short s16x4 __attribute__((ext_vector_type(4)));
typedef unsigned u32x2 __attribute__((ext_vector_type(2)));
typedef unsigned u32x4 __attribute__((ext_vector_type(4)));

#define BB 4
#define SS 2048
#define EE 1024
#define HH 16
#define DH 64
#define PLANE (SS * DH)   // 131072 elements per (mat,b,h) plane

__device__ __forceinline__ u16 f32_to_bf16(float f) {
  unsigned u = __builtin_bit_cast(unsigned, f);
  u += 0x7fffu + ((u >> 16) & 1u);
  return (u16)(u >> 16);
}

// pack two f32 -> bf16x2 (truncating) in ONE v_perm_b32
__device__ __forceinline__ unsigned pack_bf16_trunc(float lo, float hi) {
  return __builtin_amdgcn_perm(__builtin_bit_cast(unsigned, hi),
                               __builtin_bit_cast(unsigned, lo), 0x07060302u);
}

__device__ __forceinline__ void async_copy16(const void* g, void* lds) {
  __builtin_amdgcn_global_load_lds(
      (const __attribute__((address_space(1))) void*)g,
      (__attribute__((address_space(3))) void*)lds, 16, 0, 0);
}

// exp2 — R1-R4/R6 proven-correct gated form (R5's bare asm failed: TRANS-op use
// hazard not visible to the hazard recognizer through an opaque asm blob).
__device__ __forceinline__ float ex2(float x) {
#if __has_builtin(__builtin_amdgcn_exp2f)
  return __builtin_amdgcn_exp2f(x);
#else
  float r;
  asm("v_exp_f32 %0, %1\n\ts_nop 1" : "=v"(r) : "v"(x));
  return r;
#endif
}

// ---------------- x fp32 -> bf16 ----------------
__global__ void cvt_x_kernel(const float* __restrict__ x, u16* __restrict__ xb) {
  int i = (blockIdx.x * 256 + threadIdx.x) * 8;
  float4 a = *(const float4*)(x + i);
  float4 c = *(const float4*)(x + i + 4);
  u16x8 o;
  o[0] = f32_to_bf16(a.x); o[1] = f32_to_bf16(a.y);
  o[2] = f32_to_bf16(a.z); o[3] = f32_to_bf16(a.w);
  o[4] = f32_to_bf16(c.x); o[5] = f32_to_bf16(c.y);
  o[6] = f32_to_bf16(c.z); o[7] = f32_to_bf16(c.w);
  *(u16x8*)(xb + i) = o;
}

// ---------------- W fp32 [k][e] -> bf16 W^T [n=mat*1024+e][k] ----------------
__global__ void cvt_w_kernel(const float* __restrict__ Wq, const float* __restrict__ Wk,
                             const float* __restrict__ Wv, u16* __restrict__ wb) {
  __shared__ u16 T[64 * 72];
  int mat = blockIdx.z;
  const float* W = (mat == 0) ? Wq : ((mat == 1) ? Wk : Wv);
  int e0 = blockIdx.x * 64, k0 = blockIdx.y * 64;
  int t = threadIdx.x;
  int tr = t >> 4, tc = t & 15;
  for (int i = 0; i < 4; ++i) {
    int k = i * 16 + tr;
    float4 v = *(const float4*)(W + (k0 + k) * EE + e0 + tc * 4);
    T[(tc * 4 + 0) * 72 + k] = f32_to_bf16(v.x);
    T[(tc * 4 + 1) * 72 + k] = f32_to_bf16(v.y);
    T[(tc * 4 + 2) * 72 + k] = f32_to_bf16(v.z);
    T[(tc * 4 + 3) * 72 + k] = f32_to_bf16(v.w);
  }
  __syncthreads();
  u16* out = wb + (size_t)(mat * EE + e0) * EE + k0;
  for (int i = 0; i < 4; ++i) {
    int e = i * 16 + tr;
    u16x4 v = *(u16x4*)&T[e * 72 + tc * 4];
    *(u16x4*)(out + e * EE + tc * 4) = v;
  }
}

// ---------------- QKV GEMM: C[8192][3072] = A[8192][1024] * Bt[3072][1024]^T + bias ----
// v3 (frozen from R6): 3-buffer LDS ring -> ONE barrier per K-step + 2-step
// prefetch distance. Per step: vmcnt(4) -> s_barrier -> STAGE(kt+2) -> TILE(kt).
// Q (scaled by log2e/8) and K written [mat][b][h][s][d]; V written TRANSPOSED [b][h][d][s]
__global__ __launch_bounds__(256) void qkv_gemm_kernel(
    const u16* __restrict__ A, const u16* __restrict__ Bt,
    const float* __restrict__ bq, const float* __restrict__ bk,
    const float* __restrict__ bv, u16* __restrict__ qkv) {
  __shared__ u16 As0[128 * 32], Bs0[128 * 32];
  __shared__ u16 As1[128 * 32], Bs1[128 * 32];
  __shared__ u16 As2[128 * 32], Bs2[128 * 32];
  int tid = threadIdx.x;
  int lane = tid & 63, w = tid >> 6;
  int ln = lane & 15, quad = lane >> 4;
  int wm = w & 1, wn = w >> 1;
  int bn = blockIdx.x, bm = blockIdx.y;
  const u16* Ag = A + (size_t)bm * 128 * EE;
  const u16* Bg = Bt + (size_t)bn * 128 * EE;

  f32x4 acc[4][4] = {};

  auto STAGE = [&](u16* AsD, u16* BsD, int kt) {
    int k0 = kt * 32;
#pragma unroll
    for (int i = 0; i < 2; ++i) {
      int c = w * 128 + i * 64 + lane;
      int row = c >> 2, kc = (c & 3) * 8;
      async_copy16(Ag + row * EE + k0 + kc, AsD + (w * 128 + i * 64) * 8);
      async_copy16(Bg + row * EE + k0 + kc, BsD + (w * 128 + i * 64) * 8);
    }
  };

  auto TILE = [&](const u16* AsB, const u16* BsB) {
    __builtin_amdgcn_s_setprio(1);
    bf16x8 af[4], bfr[4];
#pragma unroll
    for (int mi = 0; mi < 4; ++mi)
      af[mi] = *(const bf16x8*)&AsB[(wm * 64 + mi * 16 + ln) * 32 + quad * 8];
#pragma unroll
    for (int ni = 0; ni < 4; ++ni)
      bfr[ni] = *(const bf16x8*)&BsB[(wn * 64 + ni * 16 + ln) * 32 + quad * 8];
#pragma unroll
    for (int mi = 0; mi < 4; ++mi)
#pragma unroll
      for (int ni = 0; ni < 4; ++ni)
        acc[mi][ni] = __builtin_amdgcn_mfma_f32_16x16x32_bf16(af[mi], bfr[ni],
                                                              acc[mi][ni], 0, 0, 0);
    __builtin_amdgcn_s_setprio(0);
  };

#define GSTEP(VM, AsC, BsC, AsN, BsN, ktn)                     \
  do {                                                         \
    asm volatile("s_waitcnt vmcnt(" #VM ")" ::: "memory");     \
    __builtin_amdgcn_sched_barrier(0);                         \
    __builtin_amdgcn_s_barrier();                              \
    __builtin_amdgcn_sched_barrier(0);                         \
    if ((ktn) < 32) STAGE(AsN, BsN, ktn);                      \
    __builtin_amdgcn_sched_barrier(0);                         \
    TILE(AsC, BsC);                                            \
  } while (0)

  STAGE(As0, Bs0, 0);
  STAGE(As1, Bs1, 1);
#pragma unroll 1
  for (int t = 0; t < 10; ++t) {
    int kt = t * 3;
    GSTEP(4, As0, Bs0, As2, Bs2, kt + 2);   // consume buf0, stage kt+2 -> buf2
    GSTEP(4, As1, Bs1, As0, Bs0, kt + 3);   // consume buf1, stage kt+3 -> buf0
    GSTEP(4, As2, Bs2, As1, Bs1, kt + 4);   // consume buf2, stage kt+4 -> buf1
  }
  GSTEP(4, As0, Bs0, As2, Bs2, 32);         // kt=30: outstanding {30,31} -> wait 30
  GSTEP(0, As1, Bs1, As2, Bs2, 32);         // kt=31: drain
#undef GSTEP

  int mat = bn >> 3;
  const float* bias = (mat == 0) ? bq : ((mat == 1) ? bk : bv);
  int b = bm >> 4;
  if (mat < 2) {
    // Q gets the softmax scale folded in (log2(e)/sqrt(64)); K scale = 1
    float scl = (mat == 0) ? 0.18033688011112042f : 1.0f;
    int base0 = (mat * BB + b) * HH * PLANE;
    for (int ni = 0; ni < 4; ++ni) {
      int e = (bn & 7) * 128 + wn * 64 + ni * 16 + ln;
      float bve = bias[e];
      int hh = e >> 6, d = e & 63;
      int cb = base0 + hh * PLANE + d;
      for (int mi = 0; mi < 4; ++mi) {
        int s0 = (bm & 15) * 128 + wm * 64 + mi * 16 + quad * 4;
        for (int r = 0; r < 4; ++r)
          qkv[cb + (s0 + r) * DH] = f32_to_bf16((acc[mi][ni][r] + bve) * scl);
      }
    }
  } else {
    // V^T: [b][h][d][s] — r spans consecutive s -> vector store
    size_t base0 = (size_t)(2 * BB + b) * HH * PLANE;
    for (int ni = 0; ni < 4; ++ni) {
      int e = (bn & 7) * 128 + wn * 64 + ni * 16 + ln;
      float bve = bias[e];
      int hh = e >> 6, d = e & 63;
      size_t cb = base0 + (size_t)hh * PLANE + (size_t)d * SS;
      for (int mi = 0; mi < 4; ++mi) {
        int s0 = (bm & 15) * 128 + wm * 64 + mi * 16 + quad * 4;
        u16x4 vv;
        for (int r = 0; r < 4; ++r) vv[r] = f32_to_bf16(acc[mi][ni][r] + bve);
        *(u16x4*)(qkv + cb + s0) = vv;
      }
    }
  }
}

// ---------------- flash attention, S^T formulation, max-free softmax ----------------
// v6: V DE-STAGED from LDS (guide lesson #7: don't stage what L2-fits). With the
// XCD plane-grouping each XCD's working set is 8 x (K+V) = 4MB = its L2, so V is
// L2-resident; the old Vs LDS tile was a verbatim copy of the V^T global layout,
// so PV B-frag reads translate 1:1 to global b64 loads with the XOR swizzle
// dropped (global is linear). LDS 32->16KB, STAGE 4->2 shots (vmcnt 4->2),
// occupancy-capped latency hiding is the point: R6 showed no pipe >45% busy with
// only ~11 waves/CU resident — the kernel idles on sync, not on work.
__global__ __launch_bounds__(256, 4) void attn_kernel(const u16* __restrict__ qkv,
                                                      float* __restrict__ out) {
  __shared__ u16 Ks0[64 * 64], Ks1[64 * 64];   // [key][d], 16B-unit swizzled
  // bijective remap over 1024 blocks: xcd = wg&7, idx = wg>>3 (0..127),
  // plane(bh) = xcd*8 + (idx>>4) (0..63), qb = idx&15.
  int wg = blockIdx.x + (blockIdx.y << 4) + (blockIdx.z << 8);
  int xcd = wg & 7, idx = wg >> 3;
  int bh = xcd * 8 + (idx >> 4);
  int qb = idx & 15;
  int h = bh & 15, b = bh >> 4;
  int t = threadIdx.x;
  int lane = t & 63, w = t >> 6;
  int ln = lane & 15, quad = lane >> 4;
  int k7 = ln & 7;
  const u16* Qg = qkv + (size_t)bh * PLANE + qb * 128 * DH;        // [s][d], pre-scaled
  const u16* Kg = qkv + (size_t)(BB * HH + bh) * PLANE;            // [s][d]
  const u16* Vg = qkv + (size_t)(2 * BB * HH + bh) * PLANE;        // [d][s]

  // staging lane map: lane l writes LDS (base + l*16B) -> row base+(l>>3), unit l&7.
  // LDS unit u of row r holds GLOBAL unit (u ^ (r&7))  =>  source unit = (l&7)^(l>>3)
  int r8 = lane >> 3, c8 = lane & 7;
  int sc8 = (c8 ^ r8) * 8;  // element offset of the pre-swizzled 16B source unit

  auto STAGE = [&](u16* KsD, int kt) {
    const u16* Kt = Kg + kt * 64 * DH;
#pragma unroll
    for (int i = 0; i < 2; ++i) {
      int row = w * 16 + i * 8 + r8;                 // row&7 == r8
      async_copy16(Kt + row * DH + sc8, KsD + (w * 16 + i * 8) * DH);
    }
  };

  // Q fragments for 2 row-blocks x 2 d-slices (B-operand: B[n=q=ln][k=d=quad*8+j])
  bf16x8 bq[2][2];
#pragma unroll
  for (int rb = 0; rb < 2; ++rb)
#pragma unroll
    for (int s = 0; s < 2; ++s)
      bq[rb][s] = *(const bf16x8*)(Qg + (w * 32 + rb * 16 + ln) * DH + s * 32 + quad * 8);

  // all-ones bf16 B-fragment for the l row-sum MFMA (key-order independent)
  u32x4 ow;
  ow[0] = ow[1] = ow[2] = ow[3] = 0x3F803F80u;
  bf16x8 ones8 = __builtin_bit_cast(bf16x8, ow);

  const f32x4 kz = {};
  f32x4 o[4][2] = {};    // [dg][rb]
  f32x4 lacc[2] = {};

  // swizzled K read offsets (elements), kt-invariant:
  // K A-frag row g*16+ln, d-slice s: LDS unit = (s*4+quad) ^ k7
  int ks0 = (quad ^ k7) * 8;
  int ks1 = ks0 ^ 32;

  // Vt = Vg + kt*64 for the tile being processed
  auto TILE = [&](const u16* Ksb, const u16* Vt) {
    __builtin_amdgcn_s_setprio(1);
    // S^T = K·Q^T : A = K rows (m=key), B = Q rows (n=q). C: (key=quad*4+r, q=ln)
    f32x4 s[2][4];
#pragma unroll
    for (int g = 0; g < 4; ++g) {
      const u16* krow = Ksb + (g * 16 + ln) * DH;
      bf16x8 kf0 = *(const bf16x8*)(krow + ks0);
      bf16x8 kf1 = *(const bf16x8*)(krow + ks1);
      s[0][g] = __builtin_amdgcn_mfma_f32_16x16x32_bf16(kf0, bq[0][0], kz, 0, 0, 0);
      s[0][g] = __builtin_amdgcn_mfma_f32_16x16x32_bf16(kf1, bq[0][1], s[0][g], 0, 0, 0);
      s[1][g] = __builtin_amdgcn_mfma_f32_16x16x32_bf16(kf0, bq[1][0], kz, 0, 0, 0);
      s[1][g] = __builtin_amdgcn_mfma_f32_16x16x32_bf16(kf1, bq[1][1], s[1][g], 0, 0, 0);
    }
    // P = exp2(sc); pack into x32 A-frags: slice G keys at (quad,j):
    //   j=0..3 -> 32G+4*quad+j (from g=2G), j=4..7 -> 32G+16+4*quad+(j-4) (g=2G+1)
    bf16x8 af[2][2];
#pragma unroll
    for (int rb = 0; rb < 2; ++rb) {
      unsigned Wd[4][2];
#pragma unroll
      for (int g = 0; g < 4; ++g) {
        Wd[g][0] = pack_bf16_trunc(ex2(s[rb][g][0]), ex2(s[rb][g][1]));
        Wd[g][1] = pack_bf16_trunc(ex2(s[rb][g][2]), ex2(s[rb][g][3]));
      }
#pragma unroll
      for (int G = 0; G < 2; ++G) {
        u32x4 aw;
        aw[0] = Wd[2 * G][0];     aw[1] = Wd[2 * G][1];
        aw[2] = Wd[2 * G + 1][0]; aw[3] = Wd[2 * G + 1][1];
        af[rb][G] = __builtin_bit_cast(bf16x8, aw);
      }
      // l += P·1 (x32, B=ones: key order irrelevant)
      lacc[rb] = __builtin_amdgcn_mfma_f32_16x16x32_bf16(af[rb][0], ones8, lacc[rb], 0, 0, 0);
      lacc[rb] = __builtin_amdgcn_mfma_f32_16x16x32_bf16(af[rb][1], ones8, lacc[rb], 0, 0, 0);
    }
    // O += P·V, V DIRECT FROM GLOBAL (L2-resident): B-frag element j for slice G
    // is V^T[d=dg*16+ln][key=32G+4*quad+{0..3 | 16..19}]. One vaddr per dg, four
    // b64 loads at immediate offsets {0,32,64,96}B — the exact image of the old
    // swizzled-LDS reads with the XOR dropped (global layout is linear).
#pragma unroll
    for (int dg = 0; dg < 4; ++dg) {
      const u16* vr = Vt + (dg * 16 + ln) * SS + 4 * quad;
      u32x2 lo0 = *(const u32x2*)(vr);
      u32x2 hi0 = *(const u32x2*)(vr + 16);
      u32x2 lo1 = *(const u32x2*)(vr + 32);
      u32x2 hi1 = *(const u32x2*)(vr + 48);
      u32x4 v0; v0[0] = lo0[0]; v0[1] = lo0[1]; v0[2] = hi0[0]; v0[3] = hi0[1];
      u32x4 v1; v1[0] = lo1[0]; v1[1] = lo1[1]; v1[2] = hi1[0]; v1[3] = hi1[1];
      bf16x8 vf0 = __builtin_bit_cast(bf16x8, v0);
      bf16x8 vf1 = __builtin_bit_cast(bf16x8, v1);
      o[dg][0] = __builtin_amdgcn_mfma_f32_16x16x32_bf16(af[0][0], vf0, o[dg][0], 0, 0, 0);
      o[dg][1] = __builtin_amdgcn_mfma_f32_16x16x32_bf16(af[1][0], vf0, o[dg][1], 0, 0, 0);
      o[dg][0] = __builtin_amdgcn_mfma_f32_16x16x32_bf16(af[0][1], vf1, o[dg][0], 0, 0, 0);
      o[dg][1] = __builtin_amdgcn_mfma_f32_16x16x32_bf16(af[1][1], vf1, o[dg][1], 0, 0, 0);
    }
    __builtin_amdgcn_s_setprio(0);
  };

  STAGE(Ks0, 0);
#pragma unroll 1
  for (int kt = 0; kt < 32; kt += 2) {
    // tile kt (buf0): prefetch K(kt+1) into buf1, wait only buf0's 2 shots.
    // (V loads issued inside TILE are fully consumed there — compiler-inserted
    // waits — so at each ledger point only the K stages are outstanding.)
    STAGE(Ks1, kt + 1);
    asm volatile("s_waitcnt vmcnt(2)" ::: "memory");
    __builtin_amdgcn_sched_barrier(0);
    __builtin_amdgcn_s_barrier();
    __builtin_amdgcn_sched_barrier(0);
    TILE(Ks0, Vg + kt * 64);
    __builtin_amdgcn_s_barrier();       // all waves done reading buf0
    // tile kt+1 (buf1): prefetch K(kt+2) into buf0 (now safe to overwrite)
    if (kt + 2 < 32) {
      STAGE(Ks0, kt + 2);
      asm volatile("s_waitcnt vmcnt(2)" ::: "memory");
    } else {
      asm volatile("s_waitcnt vmcnt(0)" ::: "memory");
    }
    __builtin_amdgcn_sched_barrier(0);
    __builtin_amdgcn_s_barrier();
    __builtin_amdgcn_sched_barrier(0);
    TILE(Ks1, Vg + (kt + 1) * 64);
    __builtin_amdgcn_s_barrier();       // all waves done reading buf1
  }

  // epilogue: O /= l ; O element (q=rb*16+quad*4+r, d=dg*16+ln); lacc[rb][r] is l(q)
  int sb = qb * 128 + w * 32;
  float* og = out + (size_t)b * SS * EE + (size_t)h * DH;
#pragma unroll
  for (int rb = 0; rb < 2; ++rb)
#pragma unroll
    for (int r = 0; r < 4; ++r) {
      float ir = 1.0f / lacc[rb][r];
      size_t qrow = (size_t)(sb + rb * 16 + quad * 4 + r);
#pragma unroll
      for (int dg = 0; dg < 4; ++dg)
        og[qrow * EE + dg * 16 + ln] = o[dg][rb][r] * ir;
    }
}

extern "C" void kernel_launch(void* const* d_in, const int* in_sizes, int n_in,
                              void* d_out, int out_size, void* d_ws, size_t ws_size,
                              hipStream_t stream) {
  (void)in_sizes; (void)n_in; (void)out_size; (void)ws_size;
  const float* x  = (const float*)d_in[0];
  const float* Wq = (const float*)d_in[1];
  const float* bq = (const float*)d_in[2];
  const float* Wk = (const float*)d_in[3];
  const float* bk = (const float*)d_in[4];
  const float* Wv = (const float*)d_in[5];
  const float* bv = (const float*)d_in[6];
  float* out = (float*)d_out;

  // scratch: x_bf16 (16MB) + W^T bf16 (6MB) in d_out (dead before attn writes);
  // QKV bf16 (48MB) in d_ws.
  u16* xb  = (u16*)d_out;
  u16* wb  = xb + (size_t)BB * SS * EE;
  u16* qkv = (u16*)d_ws;

  cvt_x_kernel<<<dim3((BB * SS * EE) / (256 * 8)), 256, 0, stream>>>(x, xb);
  cvt_w_kernel<<<dim3(16, 16, 3), 256, 0, stream>>>(Wq, Wk, Wv, wb);
  qkv_gemm_kernel<<<dim3(24, 64), 256, 0, stream>>>(xb, wb, bq, bk, bv, qkv);
  attn_kernel<<<dim3(SS / 128, HH, BB), 256, 0, stream>>>(qkv, out);
}

// Round 8
// 244.665 us; speedup vs baseline: 1.6359x; 1.6359x over previous
//
#include <hip/hip_runtime.h>
#include <math.h>

typedef unsigned short u16;
typedef __bf16 bf16x8 __attribute__((ext_vector_type(8)));
typedef float f32x4 __attribute__((ext_vector_type(4)));
typedef u16 u16x8 __attribute__((ext_vector_type(8)));
typedef u16 u16x4 __attribute__((ext_vector_type(4)));
typedef short s16x4 __attribute__((ext_vector_type(4)));
typedef unsigned u32x2 __attribute__((ext_vector_type(2)));
typedef unsigned u32x4 __attribute__((ext_vector_type(4)));

#define BB 4
#define SS 2048
#define EE 1024
#define HH 16
#define DH 64
#define PLANE (SS * DH)   // 131072 elements per (mat,b,h) plane

__device__ __forceinline__ u16 f32_to_bf16(float f) {
  unsigned u = __builtin_bit_cast(unsigned, f);
  u += 0x7fffu + ((u >> 16) & 1u);
  return (u16)(u >> 16);
}

// pack two f32 -> bf16x2 (truncating) in ONE v_perm_b32
__device__ __forceinline__ unsigned pack_bf16_trunc(float lo, float hi) {
  return __builtin_amdgcn_perm(__builtin_bit_cast(unsigned, hi),
                               __builtin_bit_cast(unsigned, lo), 0x07060302u);
}

__device__ __forceinline__ void async_copy16(const void* g, void* lds) {
  __builtin_amdgcn_global_load_lds(
      (const __attribute__((address_space(1))) void*)g,
      (__attribute__((address_space(3))) void*)lds, 16, 0, 0);
}

// exp2 — R1-R4/R6 proven-correct gated form (R5's bare asm failed: TRANS-op use
// hazard not visible to the hazard recognizer through an opaque asm blob).
__device__ __forceinline__ float ex2(float x) {
#if __has_builtin(__builtin_amdgcn_exp2f)
  return __builtin_amdgcn_exp2f(x);
#else
  float r;
  asm("v_exp_f32 %0, %1\n\ts_nop 1" : "=v"(r) : "v"(x));
  return r;
#endif
}

// ---------------- x fp32 -> bf16 ----------------
__global__ void cvt_x_kernel(const float* __restrict__ x, u16* __restrict__ xb) {
  int i = (blockIdx.x * 256 + threadIdx.x) * 8;
  float4 a = *(const float4*)(x + i);
  float4 c = *(const float4*)(x + i + 4);
  u16x8 o;
  o[0] = f32_to_bf16(a.x); o[1] = f32_to_bf16(a.y);
  o[2] = f32_to_bf16(a.z); o[3] = f32_to_bf16(a.w);
  o[4] = f32_to_bf16(c.x); o[5] = f32_to_bf16(c.y);
  o[6] = f32_to_bf16(c.z); o[7] = f32_to_bf16(c.w);
  *(u16x8*)(xb + i) = o;
}

// ---------------- W fp32 [k][e] -> bf16 W^T [n=mat*1024+e][k] ----------------
__global__ void cvt_w_kernel(const float* __restrict__ Wq, const float* __restrict__ Wk,
                             const float* __restrict__ Wv, u16* __restrict__ wb) {
  __shared__ u16 T[64 * 72];
  int mat = blockIdx.z;
  const float* W = (mat == 0) ? Wq : ((mat == 1) ? Wk : Wv);
  int e0 = blockIdx.x * 64, k0 = blockIdx.y * 64;
  int t = threadIdx.x;
  int tr = t >> 4, tc = t & 15;
  for (int i = 0; i < 4; ++i) {
    int k = i * 16 + tr;
    float4 v = *(const float4*)(W + (k0 + k) * EE + e0 + tc * 4);
    T[(tc * 4 + 0) * 72 + k] = f32_to_bf16(v.x);
    T[(tc * 4 + 1) * 72 + k] = f32_to_bf16(v.y);
    T[(tc * 4 + 2) * 72 + k] = f32_to_bf16(v.z);
    T[(tc * 4 + 3) * 72 + k] = f32_to_bf16(v.w);
  }
  __syncthreads();
  u16* out = wb + (size_t)(mat * EE + e0) * EE + k0;
  for (int i = 0; i < 4; ++i) {
    int e = i * 16 + tr;
    u16x4 v = *(u16x4*)&T[e * 72 + tc * 4];
    *(u16x4*)(out + e * EE + tc * 4) = v;
  }
}

// ---------------- QKV GEMM: C[8192][3072] = A[8192][1024] * Bt[3072][1024]^T + bias ----
// v4: BK 32->64 (halves barrier-walled K-steps 32->16) + attn's PROVEN XOR-8 LDS
// swizzle on 128B rows (the 64B-row layout's conflicts are unfixable: even rows
// can only reach banks 0-15). Staging = pre-swizzled global source (sc8) + linear
// gload_lds dest; reads use ks0=(quad^k7)*8, ks1=ks0^32 — byte-for-byte the attn
// pattern. Loop = R1-proven 2-buffer/2-barrier ledger, vmcnt(8) counted (8 shots
// per stage stay in flight across one barrier); vmcnt(0) only at the last tile.
// LDS 64KB static (2 blocks/CU). Epilogue/grid/wave-mapping unchanged.
// Q (scaled by log2e/8) and K written [mat][b][h][s][d]; V written TRANSPOSED [b][h][d][s]
__global__ __launch_bounds__(256) void qkv_gemm_kernel(
    const u16* __restrict__ A, const u16* __restrict__ Bt,
    const float* __restrict__ bq, const float* __restrict__ bk,
    const float* __restrict__ bv, u16* __restrict__ qkv) {
  __shared__ u16 As0[128 * 64], Bs0[128 * 64];
  __shared__ u16 As1[128 * 64], Bs1[128 * 64];
  int tid = threadIdx.x;
  int lane = tid & 63, w = tid >> 6;
  int ln = lane & 15, quad = lane >> 4;
  int wm = w & 1, wn = w >> 1;
  int bn = blockIdx.x, bm = blockIdx.y;
  const u16* Ag = A + (size_t)bm * 128 * EE;
  const u16* Bg = Bt + (size_t)bn * 128 * EE;

  // staging lane map (attn-proven): lane l -> row-sub r8=l>>3, unit c8=l&7;
  // LDS unit u of row r holds GLOBAL unit u^(r&7) => source unit = c8^r8.
  int r8 = lane >> 3, c8 = lane & 7;
  int sc8 = (c8 ^ r8) * 8;  // element offset of the pre-swizzled 16B source unit

  f32x4 acc[4][4] = {};

  // 8 shots per stage: 4 for A + 4 for B. Shot i covers rows i*32+w*8 .. +8.
  auto STAGE = [&](u16* AsD, u16* BsD, int kt) {
    int k0 = kt * 64;
#pragma unroll
    for (int i = 0; i < 4; ++i) {
      int row0 = i * 32 + w * 8;               // row0 % 8 == 0, so row&7 == r8
      async_copy16(Ag + (row0 + r8) * EE + k0 + sc8, AsD + (i * 256 + w * 64) * 8);
      async_copy16(Bg + (row0 + r8) * EE + k0 + sc8, BsD + (i * 256 + w * 64) * 8);
    }
  };

  // swizzled read offsets (elements), kt-invariant (attn-proven):
  int k7 = ln & 7;
  int ks0 = (quad ^ k7) * 8;   // k-slice 0: cols quad*8..+7
  int ks1 = ks0 ^ 32;          // k-slice 1: cols 32+quad*8..+7

  auto TILE = [&](const u16* AsB, const u16* BsB) {
    __builtin_amdgcn_s_setprio(1);
    bf16x8 b0[4], b1[4];
#pragma unroll
    for (int ni = 0; ni < 4; ++ni) {
      const u16* br = BsB + (wn * 64 + ni * 16 + ln) * 64;
      b0[ni] = *(const bf16x8*)(br + ks0);
      b1[ni] = *(const bf16x8*)(br + ks1);
    }
#pragma unroll
    for (int mi = 0; mi < 4; ++mi) {
      const u16* ar = AsB + (wm * 64 + mi * 16 + ln) * 64;
      bf16x8 a0 = *(const bf16x8*)(ar + ks0);
      bf16x8 a1 = *(const bf16x8*)(ar + ks1);
#pragma unroll
      for (int ni = 0; ni < 4; ++ni) {
        acc[mi][ni] = __builtin_amdgcn_mfma_f32_16x16x32_bf16(a0, b0[ni],
                                                              acc[mi][ni], 0, 0, 0);
        acc[mi][ni] = __builtin_amdgcn_mfma_f32_16x16x32_bf16(a1, b1[ni],
                                                              acc[mi][ni], 0, 0, 0);
      }
    }
    __builtin_amdgcn_s_setprio(0);
  };

  STAGE(As0, Bs0, 0);
#pragma unroll 1
  for (int kt = 0; kt < 16; kt += 2) {
    // tile kt (buf0): prefetch kt+1 into buf1; wait only buf0's 8 shots
    STAGE(As1, Bs1, kt + 1);
    asm volatile("s_waitcnt vmcnt(8)" ::: "memory");
    __builtin_amdgcn_sched_barrier(0);
    __builtin_amdgcn_s_barrier();
    __builtin_amdgcn_sched_barrier(0);
    TILE(As0, Bs0);
    __builtin_amdgcn_s_barrier();       // all waves done reading buf0
    // tile kt+1 (buf1): prefetch kt+2 into buf0 (now safe to overwrite)
    if (kt + 2 < 16) {
      STAGE(As0, Bs0, kt + 2);
      asm volatile("s_waitcnt vmcnt(8)" ::: "memory");
    } else {
      asm volatile("s_waitcnt vmcnt(0)" ::: "memory");
    }
    __builtin_amdgcn_sched_barrier(0);
    __builtin_amdgcn_s_barrier();
    __builtin_amdgcn_sched_barrier(0);
    TILE(As1, Bs1);
    __builtin_amdgcn_s_barrier();       // all waves done reading buf1
  }

  int mat = bn >> 3;
  const float* bias = (mat == 0) ? bq : ((mat == 1) ? bk : bv);
  int b = bm >> 4;
  if (mat < 2) {
    // Q gets the softmax scale folded in (log2(e)/sqrt(64)); K scale = 1
    float scl = (mat == 0) ? 0.18033688011112042f : 1.0f;
    int base0 = (mat * BB + b) * HH * PLANE;
    for (int ni = 0; ni < 4; ++ni) {
      int e = (bn & 7) * 128 + wn * 64 + ni * 16 + ln;
      float bve = bias[e];
      int hh = e >> 6, d = e & 63;
      int cb = base0 + hh * PLANE + d;
      for (int mi = 0; mi < 4; ++mi) {
        int s0 = (bm & 15) * 128 + wm * 64 + mi * 16 + quad * 4;
        for (int r = 0; r < 4; ++r)
          qkv[cb + (s0 + r) * DH] = f32_to_bf16((acc[mi][ni][r] + bve) * scl);
      }
    }
  } else {
    // V^T: [b][h][d][s] — r spans consecutive s -> vector store
    size_t base0 = (size_t)(2 * BB + b) * HH * PLANE;
    for (int ni = 0; ni < 4; ++ni) {
      int e = (bn & 7) * 128 + wn * 64 + ni * 16 + ln;
      float bve = bias[e];
      int hh = e >> 6, d = e & 63;
      size_t cb = base0 + (size_t)hh * PLANE + (size_t)d * SS;
      for (int mi = 0; mi < 4; ++mi) {
        int s0 = (bm & 15) * 128 + wm * 64 + mi * 16 + quad * 4;
        u16x4 vv;
        for (int r = 0; r < 4; ++r) vv[r] = f32_to_bf16(acc[mi][ni][r] + bve);
        *(u16x4*)(qkv + cb + s0) = vv;
      }
    }
  }
}

// ---------------- flash attention, S^T formulation, max-free softmax ----------------
// v6-revert (R6 verbatim, measured 82.1us): K AND V staged in LDS (R7 proved V
// de-staging is -3x: global b64 V loads feed MFMA directly and eat raw L2 latency).
// XCD plane-grouping remap (FETCH 153->29MB), gated ex2, x32 PV.
__global__ __launch_bounds__(256, 4) void attn_kernel(const u16* __restrict__ qkv,
                                                      float* __restrict__ out) {
  __shared__ u16 Ks0[64 * 64], Ks1[64 * 64];   // [key][d], 16B-unit swizzled
  __shared__ u16 Vs0[64 * 64], Vs1[64 * 64];   // [d][key], 16B-unit swizzled
  // bijective remap over 1024 blocks: xcd = wg&7, idx = wg>>3 (0..127),
  // plane(bh) = xcd*8 + (idx>>4) (0..63), qb = idx&15.
  int wg = blockIdx.x + (blockIdx.y << 4) + (blockIdx.z << 8);
  int xcd = wg & 7, idx = wg >> 3;
  int bh = xcd * 8 + (idx >> 4);
  int qb = idx & 15;
  int h = bh & 15, b = bh >> 4;
  int t = threadIdx.x;
  int lane = t & 63, w = t >> 6;
  int ln = lane & 15, quad = lane >> 4;
  int k7 = ln & 7;
  int q0 = quad & 1, q1 = quad >> 1;
  const u16* Qg = qkv + (size_t)bh * PLANE + qb * 128 * DH;        // [s][d], pre-scaled
  const u16* Kg = qkv + (size_t)(BB * HH + bh) * PLANE;            // [s][d]
  const u16* Vg = qkv + (size_t)(2 * BB * HH + bh) * PLANE;        // [d][s]

  // staging lane map: lane l writes LDS (base + l*16B) -> row base+(l>>3), unit l&7.
  // LDS unit u of row r holds GLOBAL unit (u ^ (r&7))  =>  source unit = (l&7)^(l>>3)
  int r8 = lane >> 3, c8 = lane & 7;
  int sc8 = (c8 ^ r8) * 8;  // element offset of the pre-swizzled 16B source unit

  auto STAGE = [&](u16* KsD, u16* VsD, int kt) {
    const u16* Kt = Kg + kt * 64 * DH;
    const u16* Vt = Vg + kt * 64;
#pragma unroll
    for (int i = 0; i < 2; ++i) {
      int row = w * 16 + i * 8 + r8;                 // row&7 == r8
      async_copy16(Kt + row * DH + sc8, KsD + (w * 16 + i * 8) * DH);
      async_copy16(Vt + row * SS + sc8, VsD + (w * 16 + i * 8) * DH);
    }
  };

  // Q fragments for 2 row-blocks x 2 d-slices (B-operand: B[n=q=ln][k=d=quad*8+j])
  bf16x8 bq[2][2];
#pragma unroll
  for (int rb = 0; rb < 2; ++rb)
#pragma unroll
    for (int s = 0; s < 2; ++s)
      bq[rb][s] = *(const bf16x8*)(Qg + (w * 32 + rb * 16 + ln) * DH + s * 32 + quad * 8);

  // all-ones bf16 B-fragment for the l row-sum MFMA (key-order independent)
  u32x4 ow;
  ow[0] = ow[1] = ow[2] = ow[3] = 0x3F803F80u;
  bf16x8 ones8 = __builtin_bit_cast(bf16x8, ow);

  const f32x4 kz = {};
  f32x4 o[4][2] = {};    // [dg][rb]
  f32x4 lacc[2] = {};

  // swizzled read offsets (elements), kt-invariant:
  // K A-frag row g*16+ln, d-slice s: LDS unit = (s*4+quad) ^ k7
  int ks0 = (quad ^ k7) * 8;
  int ks1 = ks0 ^ 32;

  auto TILE = [&](const u16* Ksb, const u16* Vsb) {
    __builtin_amdgcn_s_setprio(1);
    // S^T = K·Q^T : A = K rows (m=key), B = Q rows (n=q). C: (key=quad*4+r, q=ln)
    f32x4 s[2][4];
#pragma unroll
    for (int g = 0; g < 4; ++g) {
      const u16* krow = Ksb + (g * 16 + ln) * DH;
      bf16x8 kf0 = *(const bf16x8*)(krow + ks0);
      bf16x8 kf1 = *(const bf16x8*)(krow + ks1);
      s[0][g] = __builtin_amdgcn_mfma_f32_16x16x32_bf16(kf0, bq[0][0], kz, 0, 0, 0);
      s[0][g] = __builtin_amdgcn_mfma_f32_16x16x32_bf16(kf1, bq[0][1], s[0][g], 0, 0, 0);
      s[1][g] = __builtin_amdgcn_mfma_f32_16x16x32_bf16(kf0, bq[1][0], kz, 0, 0, 0);
      s[1][g] = __builtin_amdgcn_mfma_f32_16x16x32_bf16(kf1, bq[1][1], s[1][g], 0, 0, 0);
    }
    // P = exp2(sc); pack into x32 A-frags: slice G keys at (quad,j):
    //   j=0..3 -> 32G+4*quad+j (from g=2G), j=4..7 -> 32G+16+4*quad+(j-4) (g=2G+1)
    bf16x8 af[2][2];
#pragma unroll
    for (int rb = 0; rb < 2; ++rb) {
      unsigned Wd[4][2];
#pragma unroll
      for (int g = 0; g < 4; ++g) {
        Wd[g][0] = pack_bf16_trunc(ex2(s[rb][g][0]), ex2(s[rb][g][1]));
        Wd[g][1] = pack_bf16_trunc(ex2(s[rb][g][2]), ex2(s[rb][g][3]));
      }
#pragma unroll
      for (int G = 0; G < 2; ++G) {
        u32x4 aw;
        aw[0] = Wd[2 * G][0];     aw[1] = Wd[2 * G][1];
        aw[2] = Wd[2 * G + 1][0]; aw[3] = Wd[2 * G + 1][1];
        af[rb][G] = __builtin_bit_cast(bf16x8, aw);
      }
      // l += P·1 (x32, B=ones: key order irrelevant)
      lacc[rb] = __builtin_amdgcn_mfma_f32_16x16x32_bf16(af[rb][0], ones8, lacc[rb], 0, 0, 0);
      lacc[rb] = __builtin_amdgcn_mfma_f32_16x16x32_bf16(af[rb][1], ones8, lacc[rb], 0, 0, 0);
    }
    // O += P·V with x32: B-frag element j must be V[key(quad,j)][d=ln-col]:
    // two 8B reads per (G,dg): keys 32G+4*quad+0..3 and +16..19 from row d.
#pragma unroll
    for (int G = 0; G < 2; ++G) {
      int uLo = ((4 * G + q1) ^ k7) * 8 + 4 * q0;        // swizzled elem offset, keys 32G+4q
      int uHi = ((4 * G + q1 + 2) ^ k7) * 8 + 4 * q0;    // keys 32G+16+4q
#pragma unroll
      for (int dg = 0; dg < 4; ++dg) {
        const u16* vrow = Vsb + (dg * 16 + ln) * DH;
        u32x2 lo = *(const u32x2*)(vrow + uLo);
        u32x2 hi = *(const u32x2*)(vrow + uHi);
        u32x4 vv;
        vv[0] = lo[0]; vv[1] = lo[1]; vv[2] = hi[0]; vv[3] = hi[1];
        bf16x8 vf = __builtin_bit_cast(bf16x8, vv);
        o[dg][0] = __builtin_amdgcn_mfma_f32_16x16x32_bf16(af[0][G], vf, o[dg][0], 0, 0, 0);
        o[dg][1] = __builtin_amdgcn_mfma_f32_16x16x32_bf16(af[1][G], vf, o[dg][1], 0, 0, 0);
      }
    }
    __builtin_amdgcn_s_setprio(0);
  };

  STAGE(Ks0, Vs0, 0);
#pragma unroll 1
  for (int kt = 0; kt < 32; kt += 2) {
    // tile kt (buf0): prefetch kt+1 into buf1, wait only buf0's 4 shots
    STAGE(Ks1, Vs1, kt + 1);
    asm volatile("s_waitcnt vmcnt(4)" ::: "memory");
    __builtin_amdgcn_sched_barrier(0);
    __builtin_amdgcn_s_barrier();
    __builtin_amdgcn_sched_barrier(0);
    TILE(Ks0, Vs0);
    __builtin_amdgcn_s_barrier();       // all waves done reading buf0
    // tile kt+1 (buf1): prefetch kt+2 into buf0 (now safe to overwrite)
    if (kt + 2 < 32) {
      STAGE(Ks0, Vs0, kt + 2);
      asm volatile("s_waitcnt vmcnt(4)" ::: "memory");
    } else {
      asm volatile("s_waitcnt vmcnt(0)" ::: "memory");
    }
    __builtin_amdgcn_sched_barrier(0);
    __builtin_amdgcn_s_barrier();
    __builtin_amdgcn_sched_barrier(0);
    TILE(Ks1, Vs1);
    __builtin_amdgcn_s_barrier();       // all waves done reading buf1
  }

  // epilogue: O /= l ; O element (q=rb*16+quad*4+r, d=dg*16+ln); lacc[rb][r] is l(q)
  int sb = qb * 128 + w * 32;
  float* og = out + (size_t)b * SS * EE + (size_t)h * DH;
#pragma unroll
  for (int rb = 0; rb < 2; ++rb)
#pragma unroll
    for (int r = 0; r < 4; ++r) {
      float ir = 1.0f / lacc[rb][r];
      size_t qrow = (size_t)(sb + rb * 16 + quad * 4 + r);
#pragma unroll
      for (int dg = 0; dg < 4; ++dg)
        og[qrow * EE + dg * 16 + ln] = o[dg][rb][r] * ir;
    }
}

extern "C" void kernel_launch(void* const* d_in, const int* in_sizes, int n_in,
                              void* d_out, int out_size, void* d_ws, size_t ws_size,
                              hipStream_t stream) {
  (void)in_sizes; (void)n_in; (void)out_size; (void)ws_size;
  const float* x  = (const float*)d_in[0];
  const float* Wq = (const float*)d_in[1];
  const float* bq = (const float*)d_in[2];
  const float* Wk = (const float*)d_in[3];
  const float* bk = (const float*)d_in[4];
  const float* Wv = (const float*)d_in[5];
  const float* bv = (const float*)d_in[6];
  float* out = (float*)d_out;

  // scratch: x_bf16 (16MB) + W^T bf16 (6MB) in d_out (dead before attn writes);
  // QKV bf16 (48MB) in d_ws.
  u16* xb  = (u16*)d_out;
  u16* wb  = xb + (size_t)BB * SS * EE;
  u16* qkv = (u16*)d_ws;

  cvt_x_kernel<<<dim3((BB * SS * EE) / (256 * 8)), 256, 0, stream>>>(x, xb);
  cvt_w_kernel<<<dim3(16, 16, 3), 256, 0, stream>>>(Wq, Wk, Wv, wb);
  qkv_gemm_kernel<<<dim3(24, 64), 256, 0, stream>>>(xb, wb, bq, bk, bv, qkv);
  attn_kernel<<<dim3(SS / 128, HH, BB), 256, 0, stream>>>(qkv, out);
}

// Round 9
// 226.769 us; speedup vs baseline: 1.7650x; 1.0789x over previous
//
#include <hip/hip_runtime.h>
#include <math.h>

typedef unsigned short u16;
typedef __bf16 bf16x8 __attribute__((ext_vector_type(8)));
typedef float f32x4 __attribute__((ext_vector_type(4)));
typedef u16 u16x8 __attribute__((ext_vector_type(8)));
typedef u16 u16x4 __attribute__((ext_vector_type(4)));
typedef short s16x4 __attribute__((ext_vector_type(4)));
typedef unsigned u32x2 __attribute__((ext_vector_type(2)));
typedef unsigned u32x4 __attribute__((ext_vector_type(4)));

#define BB 4
#define SS 2048
#define EE 1024
#define HH 16
#define DH 64
#define PLANE (SS * DH)   // 131072 elements per (mat,b,h) plane

__device__ __forceinline__ u16 f32_to_bf16(float f) {
  unsigned u = __builtin_bit_cast(unsigned, f);
  u += 0x7fffu + ((u >> 16) & 1u);
  return (u16)(u >> 16);
}

// pack two f32 -> bf16x2 (truncating) in ONE v_perm_b32
__device__ __forceinline__ unsigned pack_bf16_trunc(float lo, float hi) {
  return __builtin_amdgcn_perm(__builtin_bit_cast(unsigned, hi),
                               __builtin_bit_cast(unsigned, lo), 0x07060302u);
}

__device__ __forceinline__ void async_copy16(const void* g, void* lds) {
  __builtin_amdgcn_global_load_lds(
      (const __attribute__((address_space(1))) void*)g,
      (__attribute__((address_space(3))) void*)lds, 16, 0, 0);
}

// exp2 — R1-R4/R6 proven-correct gated form (R5's bare asm failed: TRANS-op use
// hazard not visible to the hazard recognizer through an opaque asm blob).
__device__ __forceinline__ float ex2(float x) {
#if __has_builtin(__builtin_amdgcn_exp2f)
  return __builtin_amdgcn_exp2f(x);
#else
  float r;
  asm("v_exp_f32 %0, %1\n\ts_nop 1" : "=v"(r) : "v"(x));
  return r;
#endif
}

// ---------------- fused cvt: x fp32->bf16 AND W fp32[k][e] -> bf16 W^T ----------------
// One launch instead of two (probing the ~60us inter-kernel overhead gap).
// blocks 0..4095: x chunks; blocks 4096..4863: W transpose tiles.
__global__ __launch_bounds__(256) void cvt_kernel(
    const float* __restrict__ x, const float* __restrict__ Wq,
    const float* __restrict__ Wk, const float* __restrict__ Wv,
    u16* __restrict__ xb, u16* __restrict__ wb) {
  __shared__ u16 T[64 * 72];
  int bid = blockIdx.x;
  int t = threadIdx.x;
  if (bid < 4096) {
    int i = (bid * 256 + t) * 8;
    float4 a = *(const float4*)(x + i);
    float4 c = *(const float4*)(x + i + 4);
    u16x8 o;
    o[0] = f32_to_bf16(a.x); o[1] = f32_to_bf16(a.y);
    o[2] = f32_to_bf16(a.z); o[3] = f32_to_bf16(a.w);
    o[4] = f32_to_bf16(c.x); o[5] = f32_to_bf16(c.y);
    o[6] = f32_to_bf16(c.z); o[7] = f32_to_bf16(c.w);
    *(u16x8*)(xb + i) = o;
    return;
  }
  int wid = bid - 4096;                   // 0..767
  int mat = wid >> 8, r = wid & 255;      // 3 x 256
  const float* W = (mat == 0) ? Wq : ((mat == 1) ? Wk : Wv);
  int e0 = (r & 15) * 64, k0 = (r >> 4) * 64;
  int tr = t >> 4, tc = t & 15;
  for (int i = 0; i < 4; ++i) {
    int k = i * 16 + tr;
    float4 v = *(const float4*)(W + (k0 + k) * EE + e0 + tc * 4);
    T[(tc * 4 + 0) * 72 + k] = f32_to_bf16(v.x);
    T[(tc * 4 + 1) * 72 + k] = f32_to_bf16(v.y);
    T[(tc * 4 + 2) * 72 + k] = f32_to_bf16(v.z);
    T[(tc * 4 + 3) * 72 + k] = f32_to_bf16(v.w);
  }
  __syncthreads();
  u16* out = wb + (size_t)(mat * EE + e0) * EE + k0;
  for (int i = 0; i < 4; ++i) {
    int e = i * 16 + tr;
    u16x4 v = *(u16x4*)&T[e * 72 + tc * 4];
    *(u16x4*)(out + e * EE + tc * 4) = v;
  }
}

// ---------------- QKV GEMM: C[8192][3072] = A[8192][1024] * Bt[3072][1024]^T + bias ----
// v4 (frozen from R8, passing): BK=64, XOR-8 swizzled 128B LDS rows, 2-buffer /
// 2-barrier ledger with counted vmcnt(8); vmcnt(0) only at the last tile.
// Q (scaled by log2e/8) and K written [mat][b][h][s][d]; V written TRANSPOSED [b][h][d][s]
__global__ __launch_bounds__(256) void qkv_gemm_kernel(
    const u16* __restrict__ A, const u16* __restrict__ Bt,
    const float* __restrict__ bq, const float* __restrict__ bk,
    const float* __restrict__ bv, u16* __restrict__ qkv) {
  __shared__ u16 As0[128 * 64], Bs0[128 * 64];
  __shared__ u16 As1[128 * 64], Bs1[128 * 64];
  int tid = threadIdx.x;
  int lane = tid & 63, w = tid >> 6;
  int ln = lane & 15, quad = lane >> 4;
  int wm = w & 1, wn = w >> 1;
  int bn = blockIdx.x, bm = blockIdx.y;
  const u16* Ag = A + (size_t)bm * 128 * EE;
  const u16* Bg = Bt + (size_t)bn * 128 * EE;

  int r8 = lane >> 3, c8 = lane & 7;
  int sc8 = (c8 ^ r8) * 8;  // element offset of the pre-swizzled 16B source unit

  f32x4 acc[4][4] = {};

  auto STAGE = [&](u16* AsD, u16* BsD, int kt) {
    int k0 = kt * 64;
#pragma unroll
    for (int i = 0; i < 4; ++i) {
      int row0 = i * 32 + w * 8;               // row0 % 8 == 0, so row&7 == r8
      async_copy16(Ag + (row0 + r8) * EE + k0 + sc8, AsD + (i * 256 + w * 64) * 8);
      async_copy16(Bg + (row0 + r8) * EE + k0 + sc8, BsD + (i * 256 + w * 64) * 8);
    }
  };

  int k7 = ln & 7;
  int ks0 = (quad ^ k7) * 8;   // k-slice 0: cols quad*8..+7
  int ks1 = ks0 ^ 32;          // k-slice 1: cols 32+quad*8..+7

  auto TILE = [&](const u16* AsB, const u16* BsB) {
    __builtin_amdgcn_s_setprio(1);
    bf16x8 b0[4], b1[4];
#pragma unroll
    for (int ni = 0; ni < 4; ++ni) {
      const u16* br = BsB + (wn * 64 + ni * 16 + ln) * 64;
      b0[ni] = *(const bf16x8*)(br + ks0);
      b1[ni] = *(const bf16x8*)(br + ks1);
    }
#pragma unroll
    for (int mi = 0; mi < 4; ++mi) {
      const u16* ar = AsB + (wm * 64 + mi * 16 + ln) * 64;
      bf16x8 a0 = *(const bf16x8*)(ar + ks0);
      bf16x8 a1 = *(const bf16x8*)(ar + ks1);
#pragma unroll
      for (int ni = 0; ni < 4; ++ni) {
        acc[mi][ni] = __builtin_amdgcn_mfma_f32_16x16x32_bf16(a0, b0[ni],
                                                              acc[mi][ni], 0, 0, 0);
        acc[mi][ni] = __builtin_amdgcn_mfma_f32_16x16x32_bf16(a1, b1[ni],
                                                              acc[mi][ni], 0, 0, 0);
      }
    }
    __builtin_amdgcn_s_setprio(0);
  };

  STAGE(As0, Bs0, 0);
#pragma unroll 1
  for (int kt = 0; kt < 16; kt += 2) {
    STAGE(As1, Bs1, kt + 1);
    asm volatile("s_waitcnt vmcnt(8)" ::: "memory");
    __builtin_amdgcn_sched_barrier(0);
    __builtin_amdgcn_s_barrier();
    __builtin_amdgcn_sched_barrier(0);
    TILE(As0, Bs0);
    __builtin_amdgcn_s_barrier();       // all waves done reading buf0
    if (kt + 2 < 16) {
      STAGE(As0, Bs0, kt + 2);
      asm volatile("s_waitcnt vmcnt(8)" ::: "memory");
    } else {
      asm volatile("s_waitcnt vmcnt(0)" ::: "memory");
    }
    __builtin_amdgcn_sched_barrier(0);
    __builtin_amdgcn_s_barrier();
    __builtin_amdgcn_sched_barrier(0);
    TILE(As1, Bs1);
    __builtin_amdgcn_s_barrier();       // all waves done reading buf1
  }

  int mat = bn >> 3;
  const float* bias = (mat == 0) ? bq : ((mat == 1) ? bk : bv);
  int b = bm >> 4;
  if (mat < 2) {
    // Q gets the softmax scale folded in (log2(e)/sqrt(64)); K scale = 1
    float scl = (mat == 0) ? 0.18033688011112042f : 1.0f;
    int base0 = (mat * BB + b) * HH * PLANE;
    for (int ni = 0; ni < 4; ++ni) {
      int e = (bn & 7) * 128 + wn * 64 + ni * 16 + ln;
      float bve = bias[e];
      int hh = e >> 6, d = e & 63;
      int cb = base0 + hh * PLANE + d;
      for (int mi = 0; mi < 4; ++mi) {
        int s0 = (bm & 15) * 128 + wm * 64 + mi * 16 + quad * 4;
        for (int r = 0; r < 4; ++r)
          qkv[cb + (s0 + r) * DH] = f32_to_bf16((acc[mi][ni][r] + bve) * scl);
      }
    }
  } else {
    // V^T: [b][h][d][s] — r spans consecutive s -> vector store
    size_t base0 = (size_t)(2 * BB + b) * HH * PLANE;
    for (int ni = 0; ni < 4; ++ni) {
      int e = (bn & 7) * 128 + wn * 64 + ni * 16 + ln;
      float bve = bias[e];
      int hh = e >> 6, d = e & 63;
      size_t cb = base0 + (size_t)hh * PLANE + (size_t)d * SS;
      for (int mi = 0; mi < 4; ++mi) {
        int s0 = (bm & 15) * 128 + wm * 64 + mi * 16 + quad * 4;
        u16x4 vv;
        for (int r = 0; r < 4; ++r) vv[r] = f32_to_bf16(acc[mi][ni][r] + bve);
        *(u16x4*)(qkv + cb + s0) = vv;
      }
    }
  }
}

// ---------------- flash attention, S^T formulation, max-free softmax ----------------
// v7: QBLK 128->256 via 8 waves/block (512 threads). Per-wave math UNCHANGED from
// the proven R6 kernel (same o[4][2]/bq[2][2] footprint, same TILE) — only the
// wave count and staging map change: each K/V staging + barrier event now serves
// 2x the MFMA work (staging traffic, gload shots, barrier events per CU halve).
// STAGE = 1 K-shot + 1 V-shot per thread; ledger vmcnt(2), final vmcnt(0).
// Occupancy unchanged: 2 blocks x 8 waves = 16 waves/CU. XCD remap now
// 8 xcd x 8 planes x 8 qb (bijective over 512 blocks).
__global__ __launch_bounds__(512, 4) void attn_kernel(const u16* __restrict__ qkv,
                                                      float* __restrict__ out) {
  __shared__ u16 Ks0[64 * 64], Ks1[64 * 64];   // [key][d], 16B-unit swizzled
  __shared__ u16 Vs0[64 * 64], Vs1[64 * 64];   // [d][key], 16B-unit swizzled
  // bijective remap over 512 blocks: xcd = wg&7, idx = wg>>3 (0..63),
  // plane(bh) = xcd*8 + (idx>>3) (0..63), qb = idx&7.
  int wg = blockIdx.x;
  int xcd = wg & 7, idx = wg >> 3;
  int bh = xcd * 8 + (idx >> 3);
  int qb = idx & 7;
  int h = bh & 15, b = bh >> 4;
  int t = threadIdx.x;
  int lane = t & 63, w = t >> 6;               // w in 0..7
  int ln = lane & 15, quad = lane >> 4;
  int k7 = ln & 7;
  int q0 = quad & 1, q1 = quad >> 1;
  const u16* Qg = qkv + (size_t)bh * PLANE + qb * 256 * DH;        // [s][d], pre-scaled
  const u16* Kg = qkv + (size_t)(BB * HH + bh) * PLANE;            // [s][d]
  const u16* Vg = qkv + (size_t)(2 * BB * HH + bh) * PLANE;        // [d][s]

  // staging lane map: wave w covers rows w*8..w*8+7; lane l -> row w*8+(l>>3),
  // unit l&7. LDS unit u of row r holds GLOBAL unit u^(r&7); row&7 == l>>3 == r8.
  int r8 = lane >> 3, c8 = lane & 7;
  int sc8 = (c8 ^ r8) * 8;  // element offset of the pre-swizzled 16B source unit

  auto STAGE = [&](u16* KsD, u16* VsD, int kt) {
    const u16* Kt = Kg + kt * 64 * DH;
    const u16* Vt = Vg + kt * 64;
    int row = w * 8 + r8;
    async_copy16(Kt + row * DH + sc8, KsD + (w * 8) * DH);
    async_copy16(Vt + row * SS + sc8, VsD + (w * 8) * DH);
  };

  // Q fragments for 2 row-blocks x 2 d-slices (B-operand: B[n=q=ln][k=d=quad*8+j])
  bf16x8 bq[2][2];
#pragma unroll
  for (int rb = 0; rb < 2; ++rb)
#pragma unroll
    for (int s = 0; s < 2; ++s)
      bq[rb][s] = *(const bf16x8*)(Qg + (w * 32 + rb * 16 + ln) * DH + s * 32 + quad * 8);

  // all-ones bf16 B-fragment for the l row-sum MFMA (key-order independent)
  u32x4 ow;
  ow[0] = ow[1] = ow[2] = ow[3] = 0x3F803F80u;
  bf16x8 ones8 = __builtin_bit_cast(bf16x8, ow);

  const f32x4 kz = {};
  f32x4 o[4][2] = {};    // [dg][rb]
  f32x4 lacc[2] = {};

  // swizzled read offsets (elements), kt-invariant:
  int ks0 = (quad ^ k7) * 8;
  int ks1 = ks0 ^ 32;

  auto TILE = [&](const u16* Ksb, const u16* Vsb) {
    __builtin_amdgcn_s_setprio(1);
    // S^T = K·Q^T : A = K rows (m=key), B = Q rows (n=q). C: (key=quad*4+r, q=ln)
    f32x4 s[2][4];
#pragma unroll
    for (int g = 0; g < 4; ++g) {
      const u16* krow = Ksb + (g * 16 + ln) * DH;
      bf16x8 kf0 = *(const bf16x8*)(krow + ks0);
      bf16x8 kf1 = *(const bf16x8*)(krow + ks1);
      s[0][g] = __builtin_amdgcn_mfma_f32_16x16x32_bf16(kf0, bq[0][0], kz, 0, 0, 0);
      s[0][g] = __builtin_amdgcn_mfma_f32_16x16x32_bf16(kf1, bq[0][1], s[0][g], 0, 0, 0);
      s[1][g] = __builtin_amdgcn_mfma_f32_16x16x32_bf16(kf0, bq[1][0], kz, 0, 0, 0);
      s[1][g] = __builtin_amdgcn_mfma_f32_16x16x32_bf16(kf1, bq[1][1], s[1][g], 0, 0, 0);
    }
    // P = exp2(sc); pack into x32 A-frags: slice G keys at (quad,j):
    //   j=0..3 -> 32G+4*quad+j (from g=2G), j=4..7 -> 32G+16+4*quad+(j-4) (g=2G+1)
    bf16x8 af[2][2];
#pragma unroll
    for (int rb = 0; rb < 2; ++rb) {
      unsigned Wd[4][2];
#pragma unroll
      for (int g = 0; g < 4; ++g) {
        Wd[g][0] = pack_bf16_trunc(ex2(s[rb][g][0]), ex2(s[rb][g][1]));
        Wd[g][1] = pack_bf16_trunc(ex2(s[rb][g][2]), ex2(s[rb][g][3]));
      }
#pragma unroll
      for (int G = 0; G < 2; ++G) {
        u32x4 aw;
        aw[0] = Wd[2 * G][0];     aw[1] = Wd[2 * G][1];
        aw[2] = Wd[2 * G + 1][0]; aw[3] = Wd[2 * G + 1][1];
        af[rb][G] = __builtin_bit_cast(bf16x8, aw);
      }
      // l += P·1 (x32, B=ones: key order irrelevant)
      lacc[rb] = __builtin_amdgcn_mfma_f32_16x16x32_bf16(af[rb][0], ones8, lacc[rb], 0, 0, 0);
      lacc[rb] = __builtin_amdgcn_mfma_f32_16x16x32_bf16(af[rb][1], ones8, lacc[rb], 0, 0, 0);
    }
    // O += P·V with x32: B-frag element j must be V[key(quad,j)][d=ln-col]:
    // two 8B reads per (G,dg): keys 32G+4*quad+0..3 and +16..19 from row d.
#pragma unroll
    for (int G = 0; G < 2; ++G) {
      int uLo = ((4 * G + q1) ^ k7) * 8 + 4 * q0;        // swizzled elem offset, keys 32G+4q
      int uHi = ((4 * G + q1 + 2) ^ k7) * 8 + 4 * q0;    // keys 32G+16+4q
#pragma unroll
      for (int dg = 0; dg < 4; ++dg) {
        const u16* vrow = Vsb + (dg * 16 + ln) * DH;
        u32x2 lo = *(const u32x2*)(vrow + uLo);
        u32x2 hi = *(const u32x2*)(vrow + uHi);
        u32x4 vv;
        vv[0] = lo[0]; vv[1] = lo[1]; vv[2] = hi[0]; vv[3] = hi[1];
        bf16x8 vf = __builtin_bit_cast(bf16x8, vv);
        o[dg][0] = __builtin_amdgcn_mfma_f32_16x16x32_bf16(af[0][G], vf, o[dg][0], 0, 0, 0);
        o[dg][1] = __builtin_amdgcn_mfma_f32_16x16x32_bf16(af[1][G], vf, o[dg][1], 0, 0, 0);
      }
    }
    __builtin_amdgcn_s_setprio(0);
  };

  STAGE(Ks0, Vs0, 0);
#pragma unroll 1
  for (int kt = 0; kt < 32; kt += 2) {
    // tile kt (buf0): prefetch kt+1 into buf1, wait only buf0's 2 shots
    STAGE(Ks1, Vs1, kt + 1);
    asm volatile("s_waitcnt vmcnt(2)" ::: "memory");
    __builtin_amdgcn_sched_barrier(0);
    __builtin_amdgcn_s_barrier();
    __builtin_amdgcn_sched_barrier(0);
    TILE(Ks0, Vs0);
    __builtin_amdgcn_s_barrier();       // all waves done reading buf0
    // tile kt+1 (buf1): prefetch kt+2 into buf0 (now safe to overwrite)
    if (kt + 2 < 32) {
      STAGE(Ks0, Vs0, kt + 2);
      asm volatile("s_waitcnt vmcnt(2)" ::: "memory");
    } else {
      asm volatile("s_waitcnt vmcnt(0)" ::: "memory");
    }
    __builtin_amdgcn_sched_barrier(0);
    __builtin_amdgcn_s_barrier();
    __builtin_amdgcn_sched_barrier(0);
    TILE(Ks1, Vs1);
    __builtin_amdgcn_s_barrier();       // all waves done reading buf1
  }

  // epilogue: O /= l ; O element (q=rb*16+quad*4+r, d=dg*16+ln); lacc[rb][r] is l(q)
  int sb = qb * 256 + w * 32;
  float* og = out + (size_t)b * SS * EE + (size_t)h * DH;
#pragma unroll
  for (int rb = 0; rb < 2; ++rb)
#pragma unroll
    for (int r = 0; r < 4; ++r) {
      float ir = 1.0f / lacc[rb][r];
      size_t qrow = (size_t)(sb + rb * 16 + quad * 4 + r);
#pragma unroll
      for (int dg = 0; dg < 4; ++dg)
        og[qrow * EE + dg * 16 + ln] = o[dg][rb][r] * ir;
    }
}

extern "C" void kernel_launch(void* const* d_in, const int* in_sizes, int n_in,
                              void* d_out, int out_size, void* d_ws, size_t ws_size,
                              hipStream_t stream) {
  (void)in_sizes; (void)n_in; (void)out_size; (void)ws_size;
  const float* x  = (const float*)d_in[0];
  const float* Wq = (const float*)d_in[1];
  const float* bq = (const float*)d_in[2];
  const float* Wk = (const float*)d_in[3];
  const float* bk = (const float*)d_in[4];
  const float* Wv = (const float*)d_in[5];
  const float* bv = (const float*)d_in[6];
  float* out = (float*)d_out;

  // scratch: x_bf16 (16MB) + W^T bf16 (6MB) in d_out (dead before attn writes);
  // QKV bf16 (48MB) in d_ws.
  u16* xb  = (u16*)d_out;
  u16* wb  = xb + (size_t)BB * SS * EE;
  u16* qkv = (u16*)d_ws;

  cvt_kernel<<<dim3(4096 + 768), 256, 0, stream>>>(x, Wq, Wk, Wv, xb, wb);
  qkv_gemm_kernel<<<dim3(24, 64), 256, 0, stream>>>(xb, wb, bq, bk, bv, qkv);
  attn_kernel<<<dim3(512), 512, 0, stream>>>(qkv, out);
}

// Round 10
// 213.859 us; speedup vs baseline: 1.8715x; 1.0604x over previous
//
#include <hip/hip_runtime.h>
#include <math.h>

typedef unsigned short u16;
typedef __bf16 bf16x8 __attribute__((ext_vector_type(8)));
typedef float f32x4 __attribute__((ext_vector_type(4)));
typedef u16 u16x8 __attribute__((ext_vector_type(8)));
typedef u16 u16x4 __attribute__((ext_vector_type(4)));
typedef short s16x4 __attribute__((ext_vector_type(4)));
typedef unsigned u32x2 __attribute__((ext_vector_type(2)));
typedef unsigned u32x4 __attribute__((ext_vector_type(4)));

#define BB 4
#define SS 2048
#define EE 1024
#define HH 16
#define DH 64
#define PLANE (SS * DH)   // 131072 elements per (mat,b,h) plane

__device__ __forceinline__ u16 f32_to_bf16(float f) {
  unsigned u = __builtin_bit_cast(unsigned, f);
  u += 0x7fffu + ((u >> 16) & 1u);
  return (u16)(u >> 16);
}

// pack two f32 -> bf16x2 (truncating) in ONE v_perm_b32
__device__ __forceinline__ unsigned pack_bf16_trunc(float lo, float hi) {
  return __builtin_amdgcn_perm(__builtin_bit_cast(unsigned, hi),
                               __builtin_bit_cast(unsigned, lo), 0x07060302u);
}

__device__ __forceinline__ void async_copy16(const void* g, void* lds) {
  __builtin_amdgcn_global_load_lds(
      (const __attribute__((address_space(1))) void*)g,
      (__attribute__((address_space(3))) void*)lds, 16, 0, 0);
}

// exp2 — R1-R4/R6 proven-correct gated form (R5's bare asm failed: TRANS-op use
// hazard not visible to the hazard recognizer through an opaque asm blob).
__device__ __forceinline__ float ex2(float x) {
#if __has_builtin(__builtin_amdgcn_exp2f)
  return __builtin_amdgcn_exp2f(x);
#else
  float r;
  asm("v_exp_f32 %0, %1\n\ts_nop 1" : "=v"(r) : "v"(x));
  return r;
#endif
}

// ---------------- fused cvt: x fp32->bf16 AND W fp32[k][e] -> bf16 W^T ----------------
__global__ __launch_bounds__(256) void cvt_kernel(
    const float* __restrict__ x, const float* __restrict__ Wq,
    const float* __restrict__ Wk, const float* __restrict__ Wv,
    u16* __restrict__ xb, u16* __restrict__ wb) {
  __shared__ u16 T[64 * 72];
  int bid = blockIdx.x;
  int t = threadIdx.x;
  if (bid < 4096) {
    int i = (bid * 256 + t) * 8;
    float4 a = *(const float4*)(x + i);
    float4 c = *(const float4*)(x + i + 4);
    u16x8 o;
    o[0] = f32_to_bf16(a.x); o[1] = f32_to_bf16(a.y);
    o[2] = f32_to_bf16(a.z); o[3] = f32_to_bf16(a.w);
    o[4] = f32_to_bf16(c.x); o[5] = f32_to_bf16(c.y);
    o[6] = f32_to_bf16(c.z); o[7] = f32_to_bf16(c.w);
    *(u16x8*)(xb + i) = o;
    return;
  }
  int wid = bid - 4096;                   // 0..767
  int mat = wid >> 8, r = wid & 255;      // 3 x 256
  const float* W = (mat == 0) ? Wq : ((mat == 1) ? Wk : Wv);
  int e0 = (r & 15) * 64, k0 = (r >> 4) * 64;
  int tr = t >> 4, tc = t & 15;
  for (int i = 0; i < 4; ++i) {
    int k = i * 16 + tr;
    float4 v = *(const float4*)(W + (k0 + k) * EE + e0 + tc * 4);
    T[(tc * 4 + 0) * 72 + k] = f32_to_bf16(v.x);
    T[(tc * 4 + 1) * 72 + k] = f32_to_bf16(v.y);
    T[(tc * 4 + 2) * 72 + k] = f32_to_bf16(v.z);
    T[(tc * 4 + 3) * 72 + k] = f32_to_bf16(v.w);
  }
  __syncthreads();
  u16* out = wb + (size_t)(mat * EE + e0) * EE + k0;
  for (int i = 0; i < 4; ++i) {
    int e = i * 16 + tr;
    u16x4 v = *(u16x4*)&T[e * 72 + tc * 4];
    *(u16x4*)(out + e * EE + tc * 4) = v;
  }
}

// ---------------- QKV GEMM: C[8192][3072] = A[8192][1024] * Bt[3072][1024]^T + bias ----
// v4 (frozen structure from R8) + ONE change: the V^T epilogue now writes keys at
// PERMUTED in-tile position L(16t+4q+r) = 16q + 8(t>>1) + 4(t&1) + r within each
// 64-key tile-row. This makes attn's PV x32 B-fragment a single aligned b128 LDS
// read (keys 32G+4q+{0..3} and 32G+16+4q+{0..3} land contiguous). The u16x4
// vector store is preserved (r is the fast axis of L).
// Q (scaled by log2e/8) and K written [mat][b][h][s][d]; V written [b][h][d][perm-s]
__global__ __launch_bounds__(256) void qkv_gemm_kernel(
    const u16* __restrict__ A, const u16* __restrict__ Bt,
    const float* __restrict__ bq, const float* __restrict__ bk,
    const float* __restrict__ bv, u16* __restrict__ qkv) {
  __shared__ u16 As0[128 * 64], Bs0[128 * 64];
  __shared__ u16 As1[128 * 64], Bs1[128 * 64];
  int tid = threadIdx.x;
  int lane = tid & 63, w = tid >> 6;
  int ln = lane & 15, quad = lane >> 4;
  int wm = w & 1, wn = w >> 1;
  int bn = blockIdx.x, bm = blockIdx.y;
  const u16* Ag = A + (size_t)bm * 128 * EE;
  const u16* Bg = Bt + (size_t)bn * 128 * EE;

  int r8 = lane >> 3, c8 = lane & 7;
  int sc8 = (c8 ^ r8) * 8;  // element offset of the pre-swizzled 16B source unit

  f32x4 acc[4][4] = {};

  auto STAGE = [&](u16* AsD, u16* BsD, int kt) {
    int k0 = kt * 64;
#pragma unroll
    for (int i = 0; i < 4; ++i) {
      int row0 = i * 32 + w * 8;               // row0 % 8 == 0, so row&7 == r8
      async_copy16(Ag + (row0 + r8) * EE + k0 + sc8, AsD + (i * 256 + w * 64) * 8);
      async_copy16(Bg + (row0 + r8) * EE + k0 + sc8, BsD + (i * 256 + w * 64) * 8);
    }
  };

  int k7 = ln & 7;
  int ks0 = (quad ^ k7) * 8;   // k-slice 0: cols quad*8..+7
  int ks1 = ks0 ^ 32;          // k-slice 1: cols 32+quad*8..+7

  auto TILE = [&](const u16* AsB, const u16* BsB) {
    __builtin_amdgcn_s_setprio(1);
    bf16x8 b0[4], b1[4];
#pragma unroll
    for (int ni = 0; ni < 4; ++ni) {
      const u16* br = BsB + (wn * 64 + ni * 16 + ln) * 64;
      b0[ni] = *(const bf16x8*)(br + ks0);
      b1[ni] = *(const bf16x8*)(br + ks1);
    }
#pragma unroll
    for (int mi = 0; mi < 4; ++mi) {
      const u16* ar = AsB + (wm * 64 + mi * 16 + ln) * 64;
      bf16x8 a0 = *(const bf16x8*)(ar + ks0);
      bf16x8 a1 = *(const bf16x8*)(ar + ks1);
#pragma unroll
      for (int ni = 0; ni < 4; ++ni) {
        acc[mi][ni] = __builtin_amdgcn_mfma_f32_16x16x32_bf16(a0, b0[ni],
                                                              acc[mi][ni], 0, 0, 0);
        acc[mi][ni] = __builtin_amdgcn_mfma_f32_16x16x32_bf16(a1, b1[ni],
                                                              acc[mi][ni], 0, 0, 0);
      }
    }
    __builtin_amdgcn_s_setprio(0);
  };

  STAGE(As0, Bs0, 0);
#pragma unroll 1
  for (int kt = 0; kt < 16; kt += 2) {
    STAGE(As1, Bs1, kt + 1);
    asm volatile("s_waitcnt vmcnt(8)" ::: "memory");
    __builtin_amdgcn_sched_barrier(0);
    __builtin_amdgcn_s_barrier();
    __builtin_amdgcn_sched_barrier(0);
    TILE(As0, Bs0);
    __builtin_amdgcn_s_barrier();       // all waves done reading buf0
    if (kt + 2 < 16) {
      STAGE(As0, Bs0, kt + 2);
      asm volatile("s_waitcnt vmcnt(8)" ::: "memory");
    } else {
      asm volatile("s_waitcnt vmcnt(0)" ::: "memory");
    }
    __builtin_amdgcn_sched_barrier(0);
    __builtin_amdgcn_s_barrier();
    __builtin_amdgcn_sched_barrier(0);
    TILE(As1, Bs1);
    __builtin_amdgcn_s_barrier();       // all waves done reading buf1
  }

  int mat = bn >> 3;
  const float* bias = (mat == 0) ? bq : ((mat == 1) ? bk : bv);
  int b = bm >> 4;
  if (mat < 2) {
    // Q gets the softmax scale folded in (log2(e)/sqrt(64)); K scale = 1
    float scl = (mat == 0) ? 0.18033688011112042f : 1.0f;
    int base0 = (mat * BB + b) * HH * PLANE;
    for (int ni = 0; ni < 4; ++ni) {
      int e = (bn & 7) * 128 + wn * 64 + ni * 16 + ln;
      float bve = bias[e];
      int hh = e >> 6, d = e & 63;
      int cb = base0 + hh * PLANE + d;
      for (int mi = 0; mi < 4; ++mi) {
        int s0 = (bm & 15) * 128 + wm * 64 + mi * 16 + quad * 4;
        for (int r = 0; r < 4; ++r)
          qkv[cb + (s0 + r) * DH] = f32_to_bf16((acc[mi][ni][r] + bve) * scl);
      }
    }
  } else {
    // V^T: [b][h][d][perm-s] — in-tile key mi*16+quad*4+r stored at
    // L = quad*16 + (mi>>1)*8 + (mi&1)*4 + r  (r fast => vector store kept)
    size_t base0 = (size_t)(2 * BB + b) * HH * PLANE;
    for (int ni = 0; ni < 4; ++ni) {
      int e = (bn & 7) * 128 + wn * 64 + ni * 16 + ln;
      float bve = bias[e];
      int hh = e >> 6, d = e & 63;
      size_t cb = base0 + (size_t)hh * PLANE + (size_t)d * SS;
      for (int mi = 0; mi < 4; ++mi) {
        int tile = (bm & 15) * 2 + wm;
        int L0 = quad * 16 + (mi >> 1) * 8 + (mi & 1) * 4;
        u16x4 vv;
        for (int r = 0; r < 4; ++r) vv[r] = f32_to_bf16(acc[mi][ni][r] + bve);
        *(u16x4*)(qkv + cb + tile * 64 + L0) = vv;
      }
    }
  }
}

// ---------------- flash attention, S^T formulation, max-free softmax ----------------
// v8: (a) V global layout pre-permuted by the producer so each PV x32 B-frag is ONE
// aligned ds_read_b128 at unit (2*quad+G)^k7 — removes 32 b64 reads + 16 register-
// pair assemblies + uLo/uHi math per tile (VALU trim). Staging code unchanged
// (linear gload_lds dest + same sc8 pre-swizzled source; the permutation rides in
// the global layout). Bank-uniform: 8 lanes/unit, 8 touches/bank = b128 minimum.
// (b) 2-tile staging rounds: 64KB LDS (2 sets x 2 tiles x K,V), proven R6 ledger
// at doubled granularity -> 1 barrier per 64-key tile (was 2), half the vmcnt
// waits. Occupancy unchanged (2 blocks x 8 waves/CU).
__global__ __launch_bounds__(512, 4) void attn_kernel(const u16* __restrict__ qkv,
                                                      float* __restrict__ out) {
  __shared__ u16 KA0[64 * 64], KA1[64 * 64], VA0[64 * 64], VA1[64 * 64];
  __shared__ u16 KB0[64 * 64], KB1[64 * 64], VB0[64 * 64], VB1[64 * 64];
  // bijective remap over 512 blocks: xcd = wg&7, idx = wg>>3 (0..63),
  // plane(bh) = xcd*8 + (idx>>3) (0..63), qb = idx&7.
  int wg = blockIdx.x;
  int xcd = wg & 7, idx = wg >> 3;
  int bh = xcd * 8 + (idx >> 3);
  int qb = idx & 7;
  int h = bh & 15, b = bh >> 4;
  int t = threadIdx.x;
  int lane = t & 63, w = t >> 6;               // w in 0..7
  int ln = lane & 15, quad = lane >> 4;
  int k7 = ln & 7;
  const u16* Qg = qkv + (size_t)bh * PLANE + qb * 256 * DH;        // [s][d], pre-scaled
  const u16* Kg = qkv + (size_t)(BB * HH + bh) * PLANE;            // [s][d]
  const u16* Vg = qkv + (size_t)(2 * BB * HH + bh) * PLANE;        // [d][perm-s]

  // staging lane map: wave w covers rows w*8..w*8+7; lane l -> row w*8+(l>>3),
  // unit l&7. LDS unit u of row r holds GLOBAL unit u^(r&7); row&7 == l>>3 == r8.
  int r8 = lane >> 3, c8 = lane & 7;
  int sc8 = (c8 ^ r8) * 8;  // element offset of the pre-swizzled 16B source unit

  // stage TWO consecutive tiles (kt, kt+1): 4 shots/thread
  auto STAGE2 = [&](u16* K0, u16* V0, u16* K1, u16* V1, int kt) {
    const u16* Kt = Kg + kt * 64 * DH;
    const u16* Vt = Vg + kt * 64;
    int row = w * 8 + r8;
    async_copy16(Kt + row * DH + sc8, K0 + (w * 8) * DH);
    async_copy16(Vt + row * SS + sc8, V0 + (w * 8) * DH);
    async_copy16(Kt + (64 + row) * DH + sc8, K1 + (w * 8) * DH);
    async_copy16(Vt + row * SS + 64 + sc8, V1 + (w * 8) * DH);
  };

  // Q fragments for 2 row-blocks x 2 d-slices (B-operand: B[n=q=ln][k=d=quad*8+j])
  bf16x8 bq[2][2];
#pragma unroll
  for (int rb = 0; rb < 2; ++rb)
#pragma unroll
    for (int s = 0; s < 2; ++s)
      bq[rb][s] = *(const bf16x8*)(Qg + (w * 32 + rb * 16 + ln) * DH + s * 32 + quad * 8);

  // all-ones bf16 B-fragment for the l row-sum MFMA (key-order independent)
  u32x4 ow;
  ow[0] = ow[1] = ow[2] = ow[3] = 0x3F803F80u;
  bf16x8 ones8 = __builtin_bit_cast(bf16x8, ow);

  const f32x4 kz = {};
  f32x4 o[4][2] = {};    // [dg][rb]
  f32x4 lacc[2] = {};

  // swizzled read offsets (elements), kt-invariant:
  int ks0 = (quad ^ k7) * 8;
  int ks1 = ks0 ^ 32;

  auto TILE = [&](const u16* Ksb, const u16* Vsb) {
    __builtin_amdgcn_s_setprio(1);
    // S^T = K·Q^T : A = K rows (m=key), B = Q rows (n=q). C: (key=quad*4+r, q=ln)
    f32x4 s[2][4];
#pragma unroll
    for (int g = 0; g < 4; ++g) {
      const u16* krow = Ksb + (g * 16 + ln) * DH;
      bf16x8 kf0 = *(const bf16x8*)(krow + ks0);
      bf16x8 kf1 = *(const bf16x8*)(krow + ks1);
      s[0][g] = __builtin_amdgcn_mfma_f32_16x16x32_bf16(kf0, bq[0][0], kz, 0, 0, 0);
      s[0][g] = __builtin_amdgcn_mfma_f32_16x16x32_bf16(kf1, bq[0][1], s[0][g], 0, 0, 0);
      s[1][g] = __builtin_amdgcn_mfma_f32_16x16x32_bf16(kf0, bq[1][0], kz, 0, 0, 0);
      s[1][g] = __builtin_amdgcn_mfma_f32_16x16x32_bf16(kf1, bq[1][1], s[1][g], 0, 0, 0);
    }
    // P = exp2(sc); pack into x32 A-frags: j=0..3 from g=2G (keys 32G+4q+j),
    // j=4..7 from g=2G+1 (keys 32G+16+4q+(j-4)).
    bf16x8 af[2][2];
#pragma unroll
    for (int rb = 0; rb < 2; ++rb) {
      unsigned Wd[4][2];
#pragma unroll
      for (int g = 0; g < 4; ++g) {
        Wd[g][0] = pack_bf16_trunc(ex2(s[rb][g][0]), ex2(s[rb][g][1]));
        Wd[g][1] = pack_bf16_trunc(ex2(s[rb][g][2]), ex2(s[rb][g][3]));
      }
#pragma unroll
      for (int G = 0; G < 2; ++G) {
        u32x4 aw;
        aw[0] = Wd[2 * G][0];     aw[1] = Wd[2 * G][1];
        aw[2] = Wd[2 * G + 1][0]; aw[3] = Wd[2 * G + 1][1];
        af[rb][G] = __builtin_bit_cast(bf16x8, aw);
      }
      // l += P·1 (x32, B=ones: key order irrelevant)
      lacc[rb] = __builtin_amdgcn_mfma_f32_16x16x32_bf16(af[rb][0], ones8, lacc[rb], 0, 0, 0);
      lacc[rb] = __builtin_amdgcn_mfma_f32_16x16x32_bf16(af[rb][1], ones8, lacc[rb], 0, 0, 0);
    }
    // O += P·V: producer pre-permuted V rows, so B-frag (G,dg) is ONE b128 at
    // unit (2*quad+G)^k7 of row d = dg*16+ln.
#pragma unroll
    for (int G = 0; G < 2; ++G) {
#pragma unroll
      for (int dg = 0; dg < 4; ++dg) {
        const u16* vrow = Vsb + (dg * 16 + ln) * DH;
        bf16x8 vf = *(const bf16x8*)(vrow + ((2 * quad + G) ^ k7) * 8);
        o[dg][0] = __builtin_amdgcn_mfma_f32_16x16x32_bf16(af[0][G], vf, o[dg][0], 0, 0, 0);
        o[dg][1] = __builtin_amdgcn_mfma_f32_16x16x32_bf16(af[1][G], vf, o[dg][1], 0, 0, 0);
      }
    }
    __builtin_amdgcn_s_setprio(0);
  };

  STAGE2(KA0, VA0, KA1, VA1, 0);
#pragma unroll 1
  for (int rt = 0; rt < 32; rt += 4) {
    // round A (tiles rt, rt+1): prefetch B <- tiles rt+2, rt+3
    STAGE2(KB0, VB0, KB1, VB1, rt + 2);
    asm volatile("s_waitcnt vmcnt(4)" ::: "memory");   // A's 4 shots landed, B's in flight
    __builtin_amdgcn_sched_barrier(0);
    __builtin_amdgcn_s_barrier();
    __builtin_amdgcn_sched_barrier(0);
    TILE(KA0, VA0);
    TILE(KA1, VA1);
    __builtin_amdgcn_s_barrier();       // all waves done reading set A
    // round B (tiles rt+2, rt+3): prefetch A <- tiles rt+4, rt+5
    if (rt + 4 < 32) {
      STAGE2(KA0, VA0, KA1, VA1, rt + 4);
      asm volatile("s_waitcnt vmcnt(4)" ::: "memory"); // B's 4 landed, A's in flight
    } else {
      asm volatile("s_waitcnt vmcnt(0)" ::: "memory");
    }
    __builtin_amdgcn_sched_barrier(0);
    __builtin_amdgcn_s_barrier();
    __builtin_amdgcn_sched_barrier(0);
    TILE(KB0, VB0);
    TILE(KB1, VB1);
    __builtin_amdgcn_s_barrier();       // all waves done reading set B
  }

  // epilogue: O /= l ; O element (q=rb*16+quad*4+r, d=dg*16+ln); lacc[rb][r] is l(q)
  int sb = qb * 256 + w * 32;
  float* og = out + (size_t)b * SS * EE + (size_t)h * DH;
#pragma unroll
  for (int rb = 0; rb < 2; ++rb)
#pragma unroll
    for (int r = 0; r < 4; ++r) {
      float ir = 1.0f / lacc[rb][r];
      size_t qrow = (size_t)(sb + rb * 16 + quad * 4 + r);
#pragma unroll
      for (int dg = 0; dg < 4; ++dg)
        og[qrow * EE + dg * 16 + ln] = o[dg][rb][r] * ir;
    }
}

extern "C" void kernel_launch(void* const* d_in, const int* in_sizes, int n_in,
                              void* d_out, int out_size, void* d_ws, size_t ws_size,
                              hipStream_t stream) {
  (void)in_sizes; (void)n_in; (void)out_size; (void)ws_size;
  const float* x  = (const float*)d_in[0];
  const float* Wq = (const float*)d_in[1];
  const float* bq = (const float*)d_in[2];
  const float* Wk = (const float*)d_in[3];
  const float* bk = (const float*)d_in[4];
  const float* Wv = (const float*)d_in[5];
  const float* bv = (const float*)d_in[6];
  float* out = (float*)d_out;

  // scratch: x_bf16 (16MB) + W^T bf16 (6MB) in d_out (dead before attn writes);
  // QKV bf16 (48MB) in d_ws.
  u16* xb  = (u16*)d_out;
  u16* wb  = xb + (size_t)BB * SS * EE;
  u16* qkv = (u16*)d_ws;

  cvt_kernel<<<dim3(4096 + 768), 256, 0, stream>>>(x, Wq, Wk, Wv, xb, wb);
  qkv_gemm_kernel<<<dim3(24, 64), 256, 0, stream>>>(xb, wb, bq, bk, bv, qkv);
  attn_kernel<<<dim3(512), 512, 0, stream>>>(qkv, out);
}